// Round 1
// baseline (108.967 us; speedup 1.0000x reference)
//
#include <hip/hip_runtime.h>
#include <hip/hip_bf16.h>

// NCC loss: five 9^3 box filters (separable) + per-voxel ncc + mean.
// Volume: B=2, D=H=W=160, fp32. Output: 1 fp32 scalar = -mean(ncc).
//
// Kernel 1: fused W+H box-sum of {f, w, f^2, w^2, f*w} per d-slice (LDS tiled).
//           Writes 5 channel-planar arrays (UNSCALED sums over 9x9) to ws.
// Kernel 2: D-axis 9-slice ring-buffer window sum + ncc math + block partials.
// Kernel 3: deterministic final reduction -> d_out[0].

constexpr int BB = 2;
constexpr int DD = 160;
constexpr int HHH = 160;
constexpr int WWW = 160;
constexpr int SLICE = HHH * WWW;            // 25600
constexpr long long NTOT = (long long)BB * DD * SLICE;  // 8,192,000

constexpr int TH = 32, TW = 32, HALO = 4;
constexpr int LH = TH + 2 * HALO;           // 40
constexpr int LW = TW + 2 * HALO;           // 40

__global__ __launch_bounds__(256) void ncc_hw_kernel(
    const float* __restrict__ f, const float* __restrict__ w,
    float* __restrict__ out) {
  __shared__ float sf[LH][LW];
  __shared__ float sw[LH][LW];
  __shared__ float t0[LH][TW];
  __shared__ float t1[LH][TW];
  __shared__ float t2[LH][TW];
  __shared__ float t3[LH][TW];
  __shared__ float t4[LH][TW];

  const int tile = blockIdx.x;              // 0..24
  const int h0 = (tile / 5) * TH;
  const int w0 = (tile % 5) * TW;
  const int d = blockIdx.y;
  const int b = blockIdx.z;
  const long long slice = (long long)(b * DD + d) * SLICE;
  const int tid = threadIdx.x;

  // Load 40x40 halo tiles of f and w (zero outside volume).
  for (int idx = tid; idx < LH * LW; idx += 256) {
    const int r = idx / LW, c = idx % LW;
    const int h = h0 + r - HALO;
    const int x = w0 + c - HALO;
    float vf = 0.f, vw = 0.f;
    if ((unsigned)h < (unsigned)HHH && (unsigned)x < (unsigned)WWW) {
      const long long g = slice + h * WWW + x;
      vf = f[g];
      vw = w[g];
    }
    sf[r][c] = vf;
    sw[r][c] = vw;
  }
  __syncthreads();

  // W-direction 9-tap sums, 5 channels, for all 40 rows x 32 output cols.
  for (int idx = tid; idx < LH * TW; idx += 256) {
    const int r = idx / TW, c = idx % TW;
    float a0 = 0.f, a1 = 0.f, a2 = 0.f, a3 = 0.f, a4 = 0.f;
#pragma unroll
    for (int k = 0; k < 9; ++k) {
      const float vf = sf[r][c + k];
      const float vw = sw[r][c + k];
      a0 += vf;
      a1 += vw;
      a2 += vf * vf;
      a3 += vw * vw;
      a4 += vf * vw;
    }
    t0[r][c] = a0;
    t1[r][c] = a1;
    t2[r][c] = a2;
    t3[r][c] = a3;
    t4[r][c] = a4;
  }
  __syncthreads();

  // H-direction 9-tap sums; write 5 channel-planar outputs.
  for (int idx = tid; idx < TH * TW; idx += 256) {
    const int r = idx / TW, c = idx % TW;
    float a0 = 0.f, a1 = 0.f, a2 = 0.f, a3 = 0.f, a4 = 0.f;
#pragma unroll
    for (int k = 0; k < 9; ++k) {
      a0 += t0[r + k][c];
      a1 += t1[r + k][c];
      a2 += t2[r + k][c];
      a3 += t3[r + k][c];
      a4 += t4[r + k][c];
    }
    const long long g = slice + (long long)(h0 + r) * WWW + (w0 + c);
    out[g] = a0;
    out[NTOT + g] = a1;
    out[2 * NTOT + g] = a2;
    out[3 * NTOT + g] = a3;
    out[4 * NTOT + g] = a4;
  }
}

// D-axis window + ncc. Grid: (200, 4). Each thread owns one (b,h,w) column
// segment of 40 d-steps; ring buffer of 9 slices x 5 channels in registers
// with STATIC shift (no runtime indexing -> no scratch).
__global__ __launch_bounds__(256) void ncc_d_kernel(
    const float* __restrict__ s, float* __restrict__ partials) {
  const int tid = threadIdx.x;
  const int g = blockIdx.x * 256 + tid;    // 0..51199
  const int b = g / SLICE;                 // blocks don't straddle b (25600%256==0)
  const int r = g % SLICE;
  const int seg = blockIdx.y;              // 0..3
  const int d0 = seg * 40;
  const long long base = (long long)b * DD * SLICE + r;

  float ring[5][9];
#pragma unroll
  for (int ch = 0; ch < 5; ++ch)
#pragma unroll
    for (int k = 0; k < 9; ++k) ring[ch][k] = 0.f;

  // Preload slices d0-4 .. d0+3 via shift-in (8 static steps).
#pragma unroll
  for (int p = 0; p < 8; ++p) {
#pragma unroll
    for (int ch = 0; ch < 5; ++ch)
#pragma unroll
      for (int k = 0; k < 8; ++k) ring[ch][k] = ring[ch][k + 1];
    const int j = d0 - 4 + p;              // < 160 always (d0 <= 120)
    if (j >= 0) {
      const long long a = base + (long long)j * SLICE;
      ring[0][8] = s[a];
      ring[1][8] = s[NTOT + a];
      ring[2][8] = s[2 * NTOT + a];
      ring[3][8] = s[3 * NTOT + a];
      ring[4][8] = s[4 * NTOT + a];
    } else {
      ring[0][8] = 0.f; ring[1][8] = 0.f; ring[2][8] = 0.f;
      ring[3][8] = 0.f; ring[4][8] = 0.f;
    }
  }

  const float inv = 1.0f / 729.0f;
  float acc = 0.f;
  for (int d = d0; d < d0 + 40; ++d) {
    // shift in slice d+4 (zero past the end)
#pragma unroll
    for (int ch = 0; ch < 5; ++ch)
#pragma unroll
      for (int k = 0; k < 8; ++k) ring[ch][k] = ring[ch][k + 1];
    const int j = d + 4;
    if (j < DD) {
      const long long a = base + (long long)j * SLICE;
      ring[0][8] = s[a];
      ring[1][8] = s[NTOT + a];
      ring[2][8] = s[2 * NTOT + a];
      ring[3][8] = s[3 * NTOT + a];
      ring[4][8] = s[4 * NTOT + a];
    } else {
      ring[0][8] = 0.f; ring[1][8] = 0.f; ring[2][8] = 0.f;
      ring[3][8] = 0.f; ring[4][8] = 0.f;
    }

    float S[5];
#pragma unroll
    for (int ch = 0; ch < 5; ++ch) {
      float a0 = 0.f;
#pragma unroll
      for (int k = 0; k < 9; ++k) a0 += ring[ch][k];
      S[ch] = a0;
    }
    const float fm = S[0] * inv;
    const float wm = S[1] * inv;
    const float fs = S[2] * inv;
    const float wsq = S[3] * inv;
    const float fw = S[4] * inv;
    const float fv = fs - fm * fm;
    const float wv = wsq - wm * wm;
    const float cov = fw - fm * wm;
    const float den = sqrtf(fmaxf(fv, 0.f) + 1e-8f) * sqrtf(fmaxf(wv, 0.f) + 1e-8f);
    const float ncc = fminf(1.f, fmaxf(-1.f, cov / den));
    acc += ncc;
  }

  __shared__ float red[256];
  red[tid] = acc;
  __syncthreads();
#pragma unroll
  for (int st = 128; st > 0; st >>= 1) {
    if (tid < st) red[tid] += red[tid + st];
    __syncthreads();
  }
  if (tid == 0) partials[blockIdx.y * gridDim.x + blockIdx.x] = red[0];
}

__global__ __launch_bounds__(256) void ncc_final_kernel(
    const float* __restrict__ partials, int n, float* __restrict__ out) {
  __shared__ float red[256];
  const int tid = threadIdx.x;
  float a = 0.f;
  for (int i = tid; i < n; i += 256) a += partials[i];
  red[tid] = a;
  __syncthreads();
#pragma unroll
  for (int st = 128; st > 0; st >>= 1) {
    if (tid < st) red[tid] += red[tid + st];
    __syncthreads();
  }
  if (tid == 0) out[0] = -red[0] * (1.0f / (float)NTOT);
}

extern "C" void kernel_launch(void* const* d_in, const int* in_sizes, int n_in,
                              void* d_out, int out_size, void* d_ws, size_t ws_size,
                              hipStream_t stream) {
  const float* fixed = (const float*)d_in[0];
  const float* warped = (const float*)d_in[1];
  float* out = (float*)d_out;
  float* ws = (float*)d_ws;

  float* chans = ws;                                    // 5 * NTOT floats
  float* partials = ws + (size_t)5 * (size_t)NTOT;      // 800 floats

  dim3 g1(25, DD, BB);
  ncc_hw_kernel<<<g1, dim3(256), 0, stream>>>(fixed, warped, chans);

  dim3 g2(200, 4);
  ncc_d_kernel<<<g2, dim3(256), 0, stream>>>(chans, partials);

  ncc_final_kernel<<<1, dim3(256), 0, stream>>>(partials, 800, out);
}

// Round 2
// 102.917 us; speedup vs baseline: 1.0588x; 1.0588x over previous
//
#include <hip/hip_runtime.h>
#include <hip/hip_bf16.h>

// NCC loss: five 9^3 box filters (separable) + per-voxel ncc + mean.
// Volume: B=2, D=H=W=160, fp32. Output: 1 fp32 scalar = -mean(ncc).
//
// K1: fused W+H box-sum of {f, w, f^2, w^2, f*w} per d-slice.
//     Incremental sliding windows, packed LDS, bf16 planar outputs (ws).
// K2: D-axis register-ring window (running sums) + ncc + block partials.
// K3: deterministic final reduction -> d_out[0].

constexpr int BB = 2;
constexpr int DD = 160;
constexpr int SLICE = 160 * 160;                         // 25600
constexpr long long NTOT = (long long)BB * DD * SLICE;   // 8,192,000

constexpr int TH = 32, TW = 32, HALO = 4;
constexpr int LH = TH + 2 * HALO;    // 40
constexpr int LW = TW + 2 * HALO;    // 40
constexpr int LWP = 42;              // padded float2 stride (84 words: 84%32=20 -> conflict-free 9-tap b64)
constexpr int TC = 33;               // t col-count pad (row stride 33*6=198 words: breaks 8-way on stores)

__global__ __launch_bounds__(256) void ncc_hw_kernel(
    const float* __restrict__ f, const float* __restrict__ w,
    __hip_bfloat16* __restrict__ out) {
  __shared__ float2 sfw[LH][LWP];      // 13.44 KB
  __shared__ float t[LH][TC][6];       // 31.68 KB  (ch 0..4 used, [5]+TC pad for banks/align)

  const int tile = blockIdx.x;               // 0..24
  const int h0 = (tile / 5) * TH;
  const int w0 = (tile % 5) * TW;
  const int d = blockIdx.y;
  const int b = blockIdx.z;
  const long long slice = (long long)(b * DD + d) * SLICE;
  const int tid = threadIdx.x;

  // ---- Phase A: stage 40x40 halo tile of (f,w) as float2, zero-padded ----
  for (int idx = tid; idx < LH * LW; idx += 256) {
    const int r = idx / LW, c = idx % LW;
    const int h = h0 + r - HALO;
    const int x = w0 + c - HALO;
    float vf = 0.f, vw = 0.f;
    if ((unsigned)h < 160u && (unsigned)x < 160u) {
      const long long g = slice + h * 160 + x;
      vf = f[g];
      vw = w[g];
    }
    sfw[r][c] = make_float2(vf, vw);
  }
  __syncthreads();

  // ---- Phase B: W-direction 9-tap sums, incremental groups of 4 cols ----
  // 40 rows x 8 groups = 320 groups.
  for (int g = tid; g < LH * 8; g += 256) {
    const int r = g / 8, c0 = (g % 8) * 4;
    float a0 = 0.f, a1 = 0.f, a2 = 0.f, a3 = 0.f, a4 = 0.f;
#pragma unroll
    for (int k = 0; k < 9; ++k) {
      const float2 v = sfw[r][c0 + k];
      a0 += v.x;
      a1 += v.y;
      a2 += v.x * v.x;
      a3 += v.y * v.y;
      a4 += v.x * v.y;
    }
    *reinterpret_cast<float2*>(&t[r][c0][0]) = make_float2(a0, a1);
    *reinterpret_cast<float2*>(&t[r][c0][2]) = make_float2(a2, a3);
    t[r][c0][4] = a4;
#pragma unroll
    for (int j = 1; j < 4; ++j) {
      const float2 vn = sfw[r][c0 + 8 + j];
      const float2 vo = sfw[r][c0 + j - 1];
      a0 += vn.x - vo.x;
      a1 += vn.y - vo.y;
      a2 += vn.x * vn.x - vo.x * vo.x;
      a3 += vn.y * vn.y - vo.y * vo.y;
      a4 += vn.x * vn.y - vo.x * vo.y;
      *reinterpret_cast<float2*>(&t[r][c0 + j][0]) = make_float2(a0, a1);
      *reinterpret_cast<float2*>(&t[r][c0 + j][2]) = make_float2(a2, a3);
      t[r][c0 + j][4] = a4;
    }
  }
  __syncthreads();

  // ---- Phase C: H-direction 9-tap sums, incremental groups of 4 rows; bf16 store ----
  // 8 r-groups x 32 cols = 256 groups (exactly 1/thread).
  {
    const int c = tid & 31;
    const int r0 = (tid >> 5) << 2;
    float s0 = 0.f, s1 = 0.f, s2 = 0.f, s3 = 0.f, s4 = 0.f;
#pragma unroll
    for (int k = 0; k < 9; ++k) {
      const float2 p01 = *reinterpret_cast<const float2*>(&t[r0 + k][c][0]);
      const float2 p23 = *reinterpret_cast<const float2*>(&t[r0 + k][c][2]);
      s0 += p01.x;
      s1 += p01.y;
      s2 += p23.x;
      s3 += p23.y;
      s4 += t[r0 + k][c][4];
    }
    long long g = slice + (long long)(h0 + r0) * 160 + (w0 + c);
    out[g] = __float2bfloat16(s0);
    out[NTOT + g] = __float2bfloat16(s1);
    out[2 * NTOT + g] = __float2bfloat16(s2);
    out[3 * NTOT + g] = __float2bfloat16(s3);
    out[4 * NTOT + g] = __float2bfloat16(s4);
#pragma unroll
    for (int j = 1; j < 4; ++j) {
      const int ro = r0 + j - 1;       // row leaving the window
      const int rn = r0 + j + 8;       // row entering
      const float2 o01 = *reinterpret_cast<const float2*>(&t[ro][c][0]);
      const float2 o23 = *reinterpret_cast<const float2*>(&t[ro][c][2]);
      const float o4 = t[ro][c][4];
      const float2 n01 = *reinterpret_cast<const float2*>(&t[rn][c][0]);
      const float2 n23 = *reinterpret_cast<const float2*>(&t[rn][c][2]);
      const float n4 = t[rn][c][4];
      s0 += n01.x - o01.x;
      s1 += n01.y - o01.y;
      s2 += n23.x - o23.x;
      s3 += n23.y - o23.y;
      s4 += n4 - o4;
      g += 160;
      out[g] = __float2bfloat16(s0);
      out[NTOT + g] = __float2bfloat16(s1);
      out[2 * NTOT + g] = __float2bfloat16(s2);
      out[3 * NTOT + g] = __float2bfloat16(s3);
      out[4 * NTOT + g] = __float2bfloat16(s4);
    }
  }
}

// D-axis window + ncc. Grid: (200, 8). Thread owns one (b,h,w) column,
// 20 d-outputs per segment. Register ring (static, fully unrolled) +
// running window sums (add new / sub 9-back).
__global__ __launch_bounds__(256) void ncc_d_kernel(
    const __hip_bfloat16* __restrict__ s, float* __restrict__ partials) {
  const int tid = threadIdx.x;
  const int col = blockIdx.x * 256 + tid;   // 0..51199
  const int b = col / SLICE;
  const int r = col % SLICE;
  const int d0 = blockIdx.y * 20;
  const long long base = (long long)b * DD * SLICE + r;

  float ring[5][9];
#pragma unroll
  for (int ch = 0; ch < 5; ++ch)
#pragma unroll
    for (int k = 0; k < 9; ++k) ring[ch][k] = 0.f;
  float S0 = 0.f, S1 = 0.f, S2 = 0.f, S3 = 0.f, S4 = 0.f;

  const float inv = 1.0f / 729.0f;
  float acc = 0.f;

#pragma unroll
  for (int p = 0; p < 28; ++p) {
    // window for output d = d0 + p - 8 covers slices [d-4, d+4]; slice
    // entering at step p is j = d0 + p - 4.
    const int j = d0 + p - 4;
    float n0 = 0.f, n1 = 0.f, n2 = 0.f, n3 = 0.f, n4 = 0.f;
    if (j >= 0 && j < DD) {
      const long long a = base + (long long)j * SLICE;
      n0 = __bfloat162float(s[a]);
      n1 = __bfloat162float(s[NTOT + a]);
      n2 = __bfloat162float(s[2 * NTOT + a]);
      n3 = __bfloat162float(s[3 * NTOT + a]);
      n4 = __bfloat162float(s[4 * NTOT + a]);
    }
    S0 += n0 - ring[0][0];
    S1 += n1 - ring[1][0];
    S2 += n2 - ring[2][0];
    S3 += n3 - ring[3][0];
    S4 += n4 - ring[4][0];
#pragma unroll
    for (int ch = 0; ch < 5; ++ch)
#pragma unroll
      for (int k = 0; k < 8; ++k) ring[ch][k] = ring[ch][k + 1];
    ring[0][8] = n0;
    ring[1][8] = n1;
    ring[2][8] = n2;
    ring[3][8] = n3;
    ring[4][8] = n4;

    if (p >= 8) {
      const float fm = S0 * inv;
      const float wm = S1 * inv;
      const float fsq = S2 * inv;
      const float wsq = S3 * inv;
      const float fw = S4 * inv;
      const float fv = fsq - fm * fm;
      const float wv = wsq - wm * wm;
      const float cov = fw - fm * wm;
      const float den = sqrtf(fmaxf(fv, 0.f) + 1e-8f) * sqrtf(fmaxf(wv, 0.f) + 1e-8f);
      acc += fminf(1.f, fmaxf(-1.f, cov / den));
    }
  }

  __shared__ float red[256];
  red[tid] = acc;
  __syncthreads();
#pragma unroll
  for (int st = 128; st > 0; st >>= 1) {
    if (tid < st) red[tid] += red[tid + st];
    __syncthreads();
  }
  if (tid == 0) partials[blockIdx.y * gridDim.x + blockIdx.x] = red[0];
}

__global__ __launch_bounds__(256) void ncc_final_kernel(
    const float* __restrict__ partials, int n, float* __restrict__ out) {
  __shared__ float red[256];
  const int tid = threadIdx.x;
  float a = 0.f;
  for (int i = tid; i < n; i += 256) a += partials[i];
  red[tid] = a;
  __syncthreads();
#pragma unroll
  for (int st = 128; st > 0; st >>= 1) {
    if (tid < st) red[tid] += red[tid + st];
    __syncthreads();
  }
  if (tid == 0) out[0] = -red[0] * (1.0f / (float)NTOT);
}

extern "C" void kernel_launch(void* const* d_in, const int* in_sizes, int n_in,
                              void* d_out, int out_size, void* d_ws, size_t ws_size,
                              hipStream_t stream) {
  const float* fixed = (const float*)d_in[0];
  const float* warped = (const float*)d_in[1];
  float* out = (float*)d_out;

  __hip_bfloat16* chans = (__hip_bfloat16*)d_ws;                    // 5*NTOT bf16 = 81.92 MB
  float* partials = (float*)((char*)d_ws + (size_t)5 * NTOT * 2);   // 1600 floats

  dim3 g1(25, DD, BB);
  ncc_hw_kernel<<<g1, dim3(256), 0, stream>>>(fixed, warped, chans);

  dim3 g2(200, 8);
  ncc_d_kernel<<<g2, dim3(256), 0, stream>>>(chans, partials);

  ncc_final_kernel<<<1, dim3(256), 0, stream>>>(partials, 1600, out);
}

// Round 3
// 88.509 us; speedup vs baseline: 1.2311x; 1.1628x over previous
//
#include <hip/hip_runtime.h>
#include <hip/hip_bf16.h>

// NCC loss: five 9^3 box filters (separable) + per-voxel ncc + mean.
// K1: per-d-slice fused W+H 9-tap box sums of {f,w,f2,w2,fw}.
//     64x32 tiles, 512 thr, bf16-packed LDS (3 blocks/CU), float4 staging,
//     channel-interleaved bf16 output (3 uints / voxel).
// K2: D-axis ring (static slot = p%9, no shifts) + ncc + block partials.
// K3: deterministic final reduction.

constexpr int BB = 2, DD = 160, HH = 160, WW = 160;
constexpr int SLICE = HH * WW;                          // 25600
constexpr long long NTOT = (long long)BB * DD * SLICE;  // 8,192,000

constexpr int TW = 64, TH = 32;
constexpr int SH = 40;        // staged rows  (TH + 8)
constexpr int SWP = 75;       // staging stride in uints (72 cols + pad, odd -> <=2-way banks)
constexpr int TPC = 67;       // W-sum pair stride (64 cols + pad, odd)

static __device__ __forceinline__ uint packbf(float x, float y) {
  __hip_bfloat16 hx = __float2bfloat16(x), hy = __float2bfloat16(y);
  ushort ux = *reinterpret_cast<ushort*>(&hx);
  ushort uy = *reinterpret_cast<ushort*>(&hy);
  return (uint)ux | ((uint)uy << 16);
}
static __device__ __forceinline__ float lof(uint u) { return __uint_as_float(u << 16); }
static __device__ __forceinline__ float hif(uint u) { return __uint_as_float(u & 0xFFFF0000u); }

__global__ __launch_bounds__(512, 6) void ncc_hw_kernel(
    const float* __restrict__ f, const float* __restrict__ w,
    uint* __restrict__ out) {
  __shared__ uint sfw[SH][SWP];       // lo16 = f bf16, hi16 = w bf16 : 12.0 KB
  __shared__ uint tp[3][SH][TPC];     // W-sum bf16x2 pairs {01,23,4-} : 32.2 KB

  const int tid = threadIdx.x;
  const int wt = blockIdx.x % 3, ht = blockIdx.x / 3;
  const int w0 = wt * TW, h0 = ht * TH;
  const int d = blockIdx.y, b = blockIdx.z;
  const long long slice = (long long)(b * DD + d) * SLICE;

  // ---- A: stage 40 rows x 72 cols of f and w via float4 (guards homogeneous
  //         per float4 since w0 % 4 == 0), packed to bf16 halves ----
  for (int i = tid; i < 2 * SH * 18; i += 512) {
    const int v = (i >= SH * 18) ? 1 : 0;          // 0=f, 1=w
    const int rem = i - v * SH * 18;
    const int r = rem / 18, g = rem % 18;
    const int h = h0 + r - 4;
    const int x0 = w0 + g * 4 - 4;
    float4 val = make_float4(0.f, 0.f, 0.f, 0.f);
    if ((unsigned)h < 160u && (unsigned)x0 < 160u) {
      const float* src = v ? w : f;
      val = *reinterpret_cast<const float4*>(src + slice + h * WW + x0);
    }
    __hip_bfloat16* dst = reinterpret_cast<__hip_bfloat16*>(&sfw[r][g * 4]);
    dst[0 * 2 + v] = __float2bfloat16(val.x);
    dst[1 * 2 + v] = __float2bfloat16(val.y);
    dst[2 * 2 + v] = __float2bfloat16(val.z);
    dst[3 * 2 + v] = __float2bfloat16(val.w);
  }
  __syncthreads();

  // ---- B: W-direction 9-tap sums, incremental groups of 4 cols.
  //         40 rows x 16 groups = 640 groups ----
  for (int g = tid; g < SH * 16; g += 512) {
    const int r = g >> 4, c0 = (g & 15) << 2;
    float a0 = 0.f, a1 = 0.f, a2 = 0.f, a3 = 0.f, a4 = 0.f;
#pragma unroll
    for (int k = 0; k < 9; ++k) {
      const uint u = sfw[r][c0 + k];
      const float fv = lof(u), wv = hif(u);
      a0 += fv; a1 += wv; a2 += fv * fv; a3 += wv * wv; a4 += fv * wv;
    }
    tp[0][r][c0] = packbf(a0, a1);
    tp[1][r][c0] = packbf(a2, a3);
    tp[2][r][c0] = packbf(a4, 0.f);
#pragma unroll
    for (int j = 1; j < 4; ++j) {
      const uint un = sfw[r][c0 + 8 + j], uo = sfw[r][c0 + j - 1];
      const float fn = lof(un), wn = hif(un), fo = lof(uo), wo = hif(uo);
      a0 += fn - fo; a1 += wn - wo;
      a2 += fn * fn - fo * fo; a3 += wn * wn - wo * wo; a4 += fn * wn - fo * wo;
      tp[0][r][c0 + j] = packbf(a0, a1);
      tp[1][r][c0 + j] = packbf(a2, a3);
      tp[2][r][c0 + j] = packbf(a4, 0.f);
    }
  }
  __syncthreads();

  // ---- C: H-direction 9-tap, incremental groups of 4 rows; interleaved
  //         bf16 store (3 uints / voxel). 8 rgroups x 64 cols = 512 ----
  {
    const int c = tid & 63;
    const int r0 = (tid >> 6) << 2;
    const int x = w0 + c;
    const bool live = (x < 160);
    float s0 = 0.f, s1 = 0.f, s2 = 0.f, s3 = 0.f, s4 = 0.f;
#pragma unroll
    for (int k = 0; k < 9; ++k) {
      const uint u01 = tp[0][r0 + k][c], u23 = tp[1][r0 + k][c], u4 = tp[2][r0 + k][c];
      s0 += lof(u01); s1 += hif(u01);
      s2 += lof(u23); s3 += hif(u23);
      s4 += lof(u4);
    }
    long long pos = slice + (long long)(h0 + r0) * WW + x;
    if (live) {
      uint* o = out + pos * 3;
      o[0] = packbf(s0, s1); o[1] = packbf(s2, s3); o[2] = packbf(s4, 0.f);
    }
#pragma unroll
    for (int j = 1; j < 4; ++j) {
      const int ro = r0 + j - 1, rn = r0 + j + 8;
      const uint o01 = tp[0][ro][c], o23 = tp[1][ro][c], o4 = tp[2][ro][c];
      const uint n01 = tp[0][rn][c], n23 = tp[1][rn][c], n4 = tp[2][rn][c];
      s0 += lof(n01) - lof(o01); s1 += hif(n01) - hif(o01);
      s2 += lof(n23) - lof(o23); s3 += hif(n23) - hif(o23);
      s4 += lof(n4) - lof(o4);
      pos += WW;
      if (live) {
        uint* o = out + pos * 3;
        o[0] = packbf(s0, s1); o[1] = packbf(s2, s3); o[2] = packbf(s4, 0.f);
      }
    }
  }
}

// D-axis window + ncc. Grid (200, 8); thread owns one (b,h,w) column,
// 20 outputs per segment; ring slot p%9 is static after full unroll.
__global__ __launch_bounds__(256) void ncc_d_kernel(
    const uint* __restrict__ s, float* __restrict__ partials) {
  const int tid = threadIdx.x;
  const int col = blockIdx.x * 256 + tid;
  const int b = col / SLICE;
  const int r = col % SLICE;
  const int d0 = blockIdx.y * 20;
  const long long base = (long long)b * DD * SLICE + r;

  float ring[5][9];
#pragma unroll
  for (int ch = 0; ch < 5; ++ch)
#pragma unroll
    for (int k = 0; k < 9; ++k) ring[ch][k] = 0.f;
  float S0 = 0.f, S1 = 0.f, S2 = 0.f, S3 = 0.f, S4 = 0.f;

  const float inv = 1.0f / 729.0f;
  float acc = 0.f;

#pragma unroll
  for (int p = 0; p < 28; ++p) {
    const int j = d0 + p - 4;
    float n0 = 0.f, n1 = 0.f, n2 = 0.f, n3 = 0.f, n4 = 0.f;
    if ((unsigned)j < 160u) {
      const uint* q = s + (base + (long long)j * SLICE) * 3;
      const uint u0 = q[0], u1 = q[1], u2 = q[2];
      n0 = lof(u0); n1 = hif(u0);
      n2 = lof(u1); n3 = hif(u1);
      n4 = lof(u2);
    }
    const int sl = p % 9;   // compile-time after unroll
    S0 += n0 - ring[0][sl]; ring[0][sl] = n0;
    S1 += n1 - ring[1][sl]; ring[1][sl] = n1;
    S2 += n2 - ring[2][sl]; ring[2][sl] = n2;
    S3 += n3 - ring[3][sl]; ring[3][sl] = n3;
    S4 += n4 - ring[4][sl]; ring[4][sl] = n4;

    if (p >= 8) {
      const float fm = S0 * inv;
      const float wm = S1 * inv;
      const float fsq = S2 * inv;
      const float wsq = S3 * inv;
      const float fw = S4 * inv;
      const float fv = fsq - fm * fm;
      const float wv = wsq - wm * wm;
      const float cov = fw - fm * wm;
      const float den = sqrtf(fmaxf(fv, 0.f) + 1e-8f) * sqrtf(fmaxf(wv, 0.f) + 1e-8f);
      acc += fminf(1.f, fmaxf(-1.f, cov / den));
    }
  }

  __shared__ float red[256];
  red[tid] = acc;
  __syncthreads();
#pragma unroll
  for (int st = 128; st > 0; st >>= 1) {
    if (tid < st) red[tid] += red[tid + st];
    __syncthreads();
  }
  if (tid == 0) partials[blockIdx.y * gridDim.x + blockIdx.x] = red[0];
}

__global__ __launch_bounds__(256) void ncc_final_kernel(
    const float* __restrict__ partials, int n, float* __restrict__ out) {
  __shared__ float red[256];
  const int tid = threadIdx.x;
  float a = 0.f;
  for (int i = tid; i < n; i += 256) a += partials[i];
  red[tid] = a;
  __syncthreads();
#pragma unroll
  for (int st = 128; st > 0; st >>= 1) {
    if (tid < st) red[tid] += red[tid + st];
    __syncthreads();
  }
  if (tid == 0) out[0] = -red[0] * (1.0f / (float)NTOT);
}

extern "C" void kernel_launch(void* const* d_in, const int* in_sizes, int n_in,
                              void* d_out, int out_size, void* d_ws, size_t ws_size,
                              hipStream_t stream) {
  const float* fixed = (const float*)d_in[0];
  const float* warped = (const float*)d_in[1];
  float* out = (float*)d_out;

  uint* chans = (uint*)d_ws;                                        // NTOT*3 uints = 98.3 MB
  float* partials = (float*)((char*)d_ws + (size_t)NTOT * 12);      // 1600 floats

  dim3 g1(15, DD, BB);     // 3 w-tiles x 5 h-tiles, 160 d, 2 b
  ncc_hw_kernel<<<g1, dim3(512), 0, stream>>>(fixed, warped, chans);

  dim3 g2(200, 8);
  ncc_d_kernel<<<g2, dim3(256), 0, stream>>>(chans, partials);

  ncc_final_kernel<<<1, dim3(256), 0, stream>>>(partials, 1600, out);
}